// Round 3
// baseline (340.570 us; speedup 1.0000x reference)
//
#include <hip/hip_runtime.h>
#include <float.h>

// Shapes (fixed by the problem)
#define Bsz 2
#define Ssz 4096
#define Hsz 12
#define Gsz 64
#define Wsz 513             // W_LOC
#define Csz (Gsz + Wsz)     // 577 channels
#define ROW (Hsz * Csz)     // 6924 floats per (b,s) row
#define HALF 256            // (Wsz-1)/2
#define RPB 8               // rows per block
#define WIN (RPB + Wsz - 1) // 520-wide output window per block

// Workspace layout (floats)
#define PSUM_SZ ((size_t)Bsz * Ssz)   // 8192
#define GACC_SZ ((size_t)Bsz * Gsz)   // 128

// K1: fused h-sum + anti-diagonal accumulation, direct-from-global.
// Block = 256 threads, 8 consecutive rows (same b since 8 | 4096).
// For fixed (r,h), consecutive threads read consecutive channels ->
// fully coalesced 256B/wave; the whole 27.7KB row is consumed by the
// block so no overfetch. No LDS staging, no per-row barriers: window
// aliasing across rows is handled by LDS atomics (ds_add_f32).
__global__ __launch_bounds__(256) void k1_fused(
    const float* __restrict__ probs, const float* __restrict__ mask,
    float* __restrict__ psum, float* __restrict__ gacc)
{
    __shared__ float win[WIN];     // 2,080 B
    const int t = threadIdx.x;
    const int row0 = blockIdx.x * RPB;
    const int b = row0 / Ssz;

    for (int w = t; w < WIN; w += 256) win[w] = 0.f;
    __syncthreads();

    float scale[RPB];
    #pragma unroll
    for (int r = 0; r < RPB; ++r)
        scale[r] = (mask[row0 + r] < 0.f) ? 0.f : 1.f;

    const float* base = probs + (size_t)row0 * ROW;
    float g = 0.f;                 // thread t<64: global channel t (Σ over r,h)

    for (int c = t; c < Csz; c += 256) {
        #pragma unroll
        for (int r = 0; r < RPB; ++r) {
            float v = 0.f;
            #pragma unroll
            for (int h = 0; h < Hsz; ++h)
                v += base[(size_t)r * ROW + h * Csz + c];
            v *= scale[r];
            if (c < Gsz) g += v;
            else atomicAdd(&win[r + (c - Gsz)], v);   // LDS atomic
        }
    }
    __syncthreads();

    // flush the 520-wide window: output i = (s0 - 256) + w
    const int i_base = (row0 - b * Ssz) - HALF;
    for (int w = t; w < WIN; w += 256) {
        const int i = i_base + w;
        if (i >= 0 && i < Ssz) atomicAdd(&psum[b * Ssz + i], win[w]);
    }
    if (t < Gsz) atomicAdd(&gacc[b * Gsz + t], g);
}

// K4: fused scatter (honors index arrays) + per-batch max + scores + mask.
// grid = B, block = 1024 (16 waves). psum row staged in LDS; gacc scatter
// applied with LDS atomics; then max-reduce and write both outputs.
__global__ __launch_bounds__(1024) void k4_final(
    const float* __restrict__ psum, const float* __restrict__ gacc,
    const float* __restrict__ thr_p,
    const int* __restrict__ loc_b, const int* __restrict__ loc_i,
    const int* __restrict__ glob_b, const int* __restrict__ glob_i,
    int n_idx, float* __restrict__ out)
{
    __shared__ float p_lds[Ssz];   // 16 KiB
    __shared__ float red[16];
    const int b = blockIdx.x;
    const int t = threadIdx.x;
    const float* p = psum + (size_t)b * Ssz;

    for (int i = t; i < Ssz; i += 1024) p_lds[i] = p[i];
    __syncthreads();

    if (t < n_idx && loc_b[t] == b)
        atomicAdd(&p_lds[loc_i[t]], gacc[glob_b[t] * Gsz + glob_i[t]]);
    __syncthreads();

    float m = -FLT_MAX;
    for (int i = t; i < Ssz; i += 1024) m = fmaxf(m, p_lds[i]);
    #pragma unroll
    for (int off = 32; off >= 1; off >>= 1) m = fmaxf(m, __shfl_down(m, off, 64));

    const int wave = t >> 6, lane = t & 63;
    if (lane == 0) red[wave] = m;
    __syncthreads();
    if (t == 0) {
        float mm = red[0];
        #pragma unroll
        for (int w = 1; w < 16; ++w) mm = fmaxf(mm, red[w]);
        red[0] = mm;
    }
    __syncthreads();
    const float mx = red[0];
    const float thr = fmaxf(1e-5f, thr_p[0]);

    for (int i = t; i < Ssz; i += 1024) {
        float sc = p_lds[i] / mx;
        out[(size_t)Bsz * Ssz + (size_t)b * Ssz + i] = sc;        // scores (output 1)
        out[(size_t)b * Ssz + i] = (sc < thr) ? -10000.f : 0.f;   // mask (output 0)
    }
}

extern "C" void kernel_launch(void* const* d_in, const int* in_sizes, int n_in,
                              void* d_out, int out_size, void* d_ws, size_t ws_size,
                              hipStream_t stream)
{
    const float* mask  = (const float*)d_in[0];
    const float* probs = (const float*)d_in[1];
    const float* thr   = (const float*)d_in[2];
    // d_in[3] = max_num_global_attn_indices (hard-coded as Gsz)
    const int* loc_b  = (const int*)d_in[4];
    const int* loc_i  = (const int*)d_in[5];
    const int* glob_b = (const int*)d_in[6];
    const int* glob_i = (const int*)d_in[7];
    const int n_idx = in_sizes[4];

    float* psum = (float*)d_ws;
    float* gacc = psum + PSUM_SZ;
    float* out  = (float*)d_out;

    // zero psum + gacc (ws is poisoned 0xAA before every launch)
    hipMemsetAsync(psum, 0, (PSUM_SZ + GACC_SZ) * sizeof(float), stream);

    k1_fused<<<dim3(Bsz * Ssz / RPB), dim3(256), 0, stream>>>(probs, mask, psum, gacc);
    k4_final<<<dim3(Bsz), dim3(1024), 0, stream>>>(psum, gacc, thr,
                                                   loc_b, loc_i, glob_b, glob_i,
                                                   n_idx, out);
}